// Round 18
// baseline (129.606 us; speedup 1.0000x reference)
//
#include <hip/hip_runtime.h>
#include <hip/hip_bf16.h>

typedef __bf16 bf16_t;
typedef __attribute__((ext_vector_type(8))) __bf16 bf16x8;
typedef __attribute__((ext_vector_type(4))) __bf16 bf16x4;
typedef __attribute__((ext_vector_type(4))) float f32x4;
typedef __attribute__((ext_vector_type(16))) float f32x16;
typedef __attribute__((ext_vector_type(2))) int i32x2;

#define B_ 2
#define T_ 2048
#define D_ 1024
#define H_ 16
#define DH_ 64
#define RS_ 3072  // fused qkv row stride

static __device__ __forceinline__ f32x4 mfma16(bf16x8 a, bf16x8 b, f32x4 c) {
  return __builtin_amdgcn_mfma_f32_16x16x32_bf16(a, b, c, 0, 0, 0);
}
static __device__ __forceinline__ f32x16 mfma32(bf16x8 a, bf16x8 b, f32x16 c) {
  return __builtin_amdgcn_mfma_f32_32x32x16_bf16(a, b, c, 0, 0, 0);
}
static __device__ __forceinline__ void gld16(const bf16_t* g, bf16_t* l) {
  __builtin_amdgcn_global_load_lds(
      (const __attribute__((address_space(1))) unsigned int*)g,
      (__attribute__((address_space(3))) unsigned int*)l, 16, 0, 0);
}
static __device__ __forceinline__ unsigned lds_addr(const bf16_t* p) {
  return (unsigned)(uintptr_t)(const __attribute__((address_space(3))) bf16_t*)p;
}
static __device__ __forceinline__ i32x2 tr64(unsigned a) {
  i32x2 d;
  asm volatile("ds_read_b64_tr_b16 %0, %1" : "=v"(d) : "v"(a));
  return d;
}
static __device__ __forceinline__ i32x2 tr64o(unsigned a) {  // +128B (4 k-rows)
  i32x2 d;
  asm volatile("ds_read_b64_tr_b16 %0, %1 offset:128" : "=v"(d) : "v"(a));
  return d;
}
static __device__ __forceinline__ unsigned pk2(float lo, float hi2) {
  unsigned short a = __builtin_bit_cast(unsigned short, (bf16_t)lo);
  unsigned short b = __builtin_bit_cast(unsigned short, (bf16_t)hi2);
  return (unsigned)a | ((unsigned)b << 16);
}

#define WAITV3 { asm volatile("s_waitcnt vmcnt(3)" ::: "memory"); __builtin_amdgcn_sched_barrier(0); }
#define WAITV4 { asm volatile("s_waitcnt vmcnt(4)" ::: "memory"); __builtin_amdgcn_sched_barrier(0); }
#define WAITV12 { asm volatile("s_waitcnt vmcnt(12)" ::: "memory"); __builtin_amdgcn_sched_barrier(0); }
#define WAITV0 { asm volatile("s_waitcnt vmcnt(0)" ::: "memory"); __builtin_amdgcn_sched_barrier(0); }
#define BAR    { __builtin_amdgcn_s_barrier(); __builtin_amdgcn_sched_barrier(0); }
#define WAITL0 { asm volatile("s_waitcnt lgkmcnt(0)" ::: "memory"); __builtin_amdgcn_sched_barrier(0); }

// ---------------- fused fp32 -> bf16 conversion (x + 4 weights, one launch) ----------------
__global__ __launch_bounds__(256) void cvt_all(const float* __restrict__ x,
                                               const float* __restrict__ w0,
                                               const float* __restrict__ w1,
                                               const float* __restrict__ w2,
                                               const float* __restrict__ w3,
                                               bf16_t* __restrict__ out) {
  const int y = blockIdx.y;
  const float* in = (y < 4) ? (x + (size_t)y * 1048576)
                            : (y == 4 ? w0 : y == 5 ? w1 : y == 6 ? w2 : w3);
  bf16_t* o = out + (size_t)y * 1048576;
  int i = blockIdx.x * 256 + threadIdx.x;
  float4 f = reinterpret_cast<const float4*>(in)[i];
  bf16x4 v;
  v[0] = (bf16_t)f.x; v[1] = (bf16_t)f.y; v[2] = (bf16_t)f.z; v[3] = (bf16_t)f.w;
  reinterpret_cast<bf16x4*>(o)[i] = v;
}

// ---------------- NT GEMM 128x128 (R7 triple-buffer BK=32, vmcnt(4), XCD swizzle) ----------------
template <bool STORE_F32, bool QSCALE>
__global__ __launch_bounds__(256) void gemm_nt(const bf16_t* __restrict__ A,
                                               const bf16_t* __restrict__ Bm,
                                               void* __restrict__ Cv,
                                               int M, int N, int K, int nbx) {
  __shared__ __align__(16) bf16_t As[3][128 * 32];
  __shared__ __align__(16) bf16_t Bs[3][128 * 32];
  const int id = blockIdx.x;
  const int nwg = gridDim.x;
  const int cpx = nwg >> 3;                    // blocks per XCD (nwg % 8 == 0)
  const int swz = (id & 7) * cpx + (id >> 3);  // bijective XCD swizzle
  const int bx = swz % nbx, by = swz / nbx;
  const int tid = threadIdx.x, lane = tid & 63, wave = tid >> 6;
  const int l15 = lane & 15;
  const int brow = by * 128, bcol = bx * 128;
  const int row0 = (wave >> 1) * 64, col0 = (wave & 1) * 64;
  const float cscale = (QSCALE && bcol < 1024) ? 0.18033688011112042f : 1.0f;

  f32x4 acc[4][4];
#pragma unroll
  for (int m = 0; m < 4; ++m)
#pragma unroll
    for (int n = 0; n < 4; ++n) acc[m][n] = f32x4{0.f, 0.f, 0.f, 0.f};

  const int nst = K >> 5;
  const int srow = tid >> 2;
  const int sc8 = (tid & 3) * 8;
  auto stage = [&](int bi, int ks) {
    const int k0 = ks * 32;
#pragma unroll
    for (int i = 0; i < 2; ++i)
      gld16(A + (size_t)(brow + 64 * i + srow) * K + k0 + sc8,
            &As[bi][2048 * i + 512 * wave]);
#pragma unroll
    for (int i = 0; i < 2; ++i)
      gld16(Bm + (size_t)(bcol + 64 * i + srow) * K + k0 + sc8,
            &Bs[bi][2048 * i + 512 * wave]);
  };

  stage(0, 0);
  stage(1, 1);

#pragma unroll 1
  for (int ks = 0; ks < nst; ++ks) {
    if (ks + 1 < nst) { WAITV4 } else { WAITV0 }
    BAR;
    if (ks + 2 < nst) stage((ks + 2) % 3, ks + 2);

    const bf16_t* Ab = &As[ks % 3][0];
    const bf16_t* Bb = &Bs[ks % 3][0];
    const int ko = (lane >> 4) * 8;
    bf16x8 af[4], bfr[4];
#pragma unroll
    for (int m = 0; m < 4; ++m)
      af[m] = *(const bf16x8*)&Ab[(row0 + 16 * m + l15) * 32 + ko];
#pragma unroll
    for (int n = 0; n < 4; ++n)
      bfr[n] = *(const bf16x8*)&Bb[(col0 + 16 * n + l15) * 32 + ko];
    WAITL0;
#pragma unroll
    for (int m = 0; m < 4; ++m)
#pragma unroll
      for (int n = 0; n < 4; ++n) acc[m][n] = mfma16(af[m], bfr[n], acc[m][n]);
  }

  const int crow = brow + row0 + (lane >> 4) * 4;
  const int ccol = bcol + col0 + l15;
#pragma unroll
  for (int m = 0; m < 4; ++m)
#pragma unroll
    for (int n = 0; n < 4; ++n)
#pragma unroll
      for (int r = 0; r < 4; ++r) {
        size_t idx = (size_t)(crow + 16 * m + r) * N + (ccol + 16 * n);
        float v = acc[m][n][r] * cscale;
        if (STORE_F32) reinterpret_cast<float*>(Cv)[idx] = v;
        else reinterpret_cast<bf16_t*>(Cv)[idx] = (bf16_t)v;
      }
}

// ---------------- NT GEMM 64x128 (out-proj, XCD swizzle) ----------------
__global__ __launch_bounds__(256) void gemm_nt64(const bf16_t* __restrict__ A,
                                                 const bf16_t* __restrict__ Bm,
                                                 float* __restrict__ Cv,
                                                 int M, int N, int K, int nbx) {
  __shared__ __align__(16) bf16_t As[3][64 * 32];
  __shared__ __align__(16) bf16_t Bs[3][128 * 32];
  const int id = blockIdx.x;
  const int cpx = gridDim.x >> 3;
  const int swz = (id & 7) * cpx + (id >> 3);
  const int bx = swz % nbx, by = swz / nbx;
  const int tid = threadIdx.x, lane = tid & 63, wave = tid >> 6;
  const int l15 = lane & 15;
  const int brow = by * 64, bcol = bx * 128;
  const int row0 = (wave >> 1) * 32, col0 = (wave & 1) * 64;

  f32x4 acc[2][4];
#pragma unroll
  for (int m = 0; m < 2; ++m)
#pragma unroll
    for (int n = 0; n < 4; ++n) acc[m][n] = f32x4{0.f, 0.f, 0.f, 0.f};

  const int nst = K >> 5;
  const int sr = lane >> 2;
  const int sc8 = (lane & 3) * 8;
  auto stage = [&](int bi, int ks) {
    const int k0 = ks * 32;
    gld16(A + (size_t)(brow + 16 * wave + sr) * K + k0 + sc8, &As[bi][512 * wave]);
#pragma unroll
    for (int i = 0; i < 2; ++i)
      gld16(Bm + (size_t)(bcol + 64 * i + 16 * wave + sr) * K + k0 + sc8,
            &Bs[bi][2048 * i + 512 * wave]);
  };

  stage(0, 0);
  stage(1, 1);

#pragma unroll 1
  for (int ks = 0; ks < nst; ++ks) {
    if (ks + 1 < nst) { WAITV3 } else { WAITV0 }
    BAR;
    if (ks + 2 < nst) stage((ks + 2) % 3, ks + 2);

    const bf16_t* Ab = &As[ks % 3][0];
    const bf16_t* Bb = &Bs[ks % 3][0];
    const int ko = (lane >> 4) * 8;
    bf16x8 af[2], bfr[4];
#pragma unroll
    for (int m = 0; m < 2; ++m)
      af[m] = *(const bf16x8*)&Ab[(row0 + 16 * m + l15) * 32 + ko];
#pragma unroll
    for (int n = 0; n < 4; ++n)
      bfr[n] = *(const bf16x8*)&Bb[(col0 + 16 * n + l15) * 32 + ko];
    WAITL0;
#pragma unroll
    for (int m = 0; m < 2; ++m)
#pragma unroll
      for (int n = 0; n < 4; ++n) acc[m][n] = mfma16(af[m], bfr[n], acc[m][n]);
  }

  const int crow = brow + row0 + (lane >> 4) * 4;
  const int ccol = bcol + col0 + l15;
#pragma unroll
  for (int m = 0; m < 2; ++m)
#pragma unroll
    for (int n = 0; n < 4; ++n)
#pragma unroll
      for (int r = 0; r < 4; ++r)
        Cv[(size_t)(crow + 16 * m + r) * N + (ccol + 16 * n)] = acc[m][n][r];
}

// ---------------- causal flash attention: R15 skeleton, 3 K-tiles per interval ----------------
// Block = 256 thr (4 waves), grid (32 bh, 8 p). Triple-intervals (192 keys each),
// ONE merged online-softmax update per interval. Phase A = ceil((2p+2)/3),
// phase B = ceil((32-2p)/3) -> exactly 12 intervals for every p (uniform).
// 2 triple-buffers ping-pong (96 KB LDS). Pipeline per interval: BAR ->
// stage(pi+1) (12 loads/thr into buf whose readers retired before the BAR) ->
// WAITV12 (drains stage(pi), leaves stage(pi+1) in flight). Per-tile
// exp->pack->PV sequencing keeps st lifetimes short (the R16 quad failure was
// holding all st+pk live -> 248 VGPR).
#define CROW(r) ((((r) & 3) + 8 * ((r) >> 2)) + 4 * hi)

__global__ __launch_bounds__(256, 1) void attn_fwd(const bf16_t* __restrict__ qkv,
                                                   bf16_t* __restrict__ ctx) {
  __shared__ __align__(128) bf16_t KV[2][3][2][4096];  // [buf][tile][K|V][4096] = 96 KB
  const int tid = threadIdx.x;
  const int lane = tid & 63;
  const int wv = tid >> 6;
  const int bh = blockIdx.x, p = blockIdx.y;
  const int b = bh >> 4, h = bh & 15;
  const bf16_t* Qg = qkv + (size_t)b * T_ * RS_ + h * DH_;
  const bf16_t* Kg = Qg + 1024;
  const bf16_t* Vg = Qg + 2048;
  bf16_t* Cg = ctx + (size_t)b * T_ * D_ + h * DH_;

  const int hi = lane >> 5;
  const int l31 = lane & 31;
  const int l15 = lane & 15;

  // stage one 64-key tile into slot [bi][tp] (K swizzled rows, V 16-wide panels)
  auto stage_t = [&](int bi, int tp, int kt) {
    bf16_t* Kb = &KV[bi][tp][0][0];
    bf16_t* Vb = &KV[bi][tp][1][0];
#pragma unroll
    for (int i = 0; i < 2; ++i) {
      int c2 = i * 256 + tid;
      int r = c2 >> 3, g8 = (c2 & 7) ^ (r & 7);
      gld16(Kg + (size_t)(kt * 64 + r) * RS_ + g8 * 8, Kb + i * 2048 + wv * 512);
    }
#pragma unroll
    for (int i = 0; i < 2; ++i) {
      int c2 = i * 256 + tid;
      int pn = c2 >> 7, k = (c2 >> 1) & 63, half = c2 & 1;
      gld16(Vg + (size_t)(kt * 64 + k) * RS_ + pn * 16 + half * 8, Vb + i * 2048 + wv * 512);
    }
  };
  auto stage_3 = [&](int bi, int ti) {
#pragma unroll
    for (int j = 0; j < 3; ++j) stage_t(bi, j, 3 * ti + j);
  };

#pragma unroll 1
  for (int phase = 0; phase < 2; ++phase) {
    const int c = phase ? (63 - 4 * p - wv) : (4 * p + wv);
    const int q0 = c * 32;
    const int mynkt = (c >> 1) + 1;  // 64-key tiles for my chunk
    const int maxp3 = phase ? ((34 - 2 * p) / 3) : ((2 * p + 4) / 3);  // uniform 12 total

    BAR;  // previous phase's LDS reads fully retired before re-staging
    stage_3(0, 0);

    bf16x8 qf[4];
#pragma unroll
    for (int d = 0; d < 4; ++d)
      qf[d] = *(const bf16x8*)&Qg[(size_t)(q0 + l31) * RS_ + d * 16 + hi * 8];

    f32x16 o[2];
#pragma unroll
    for (int n = 0; n < 2; ++n)
#pragma unroll
      for (int r = 0; r < 16; ++r) o[n][r] = 0.f;
    float mrow = -1e30f, lsum = 0.f;

#pragma unroll 1
    for (int pi = 0; pi < maxp3; ++pi) {
      BAR;  // all waves' reads of buf (pi+1)&1 (interval pi-1) retired
      if (pi + 1 < maxp3) {
        stage_3((pi + 1) & 1, pi + 1);  // newest 12 loads/thread
        WAITV12;                        // drains stage(pi); stage(pi+1) stays in flight
      } else {
        WAITV0;
      }

      const int bi = pi & 1;
      const int tb = 3 * pi;
      if (tb < mynkt) {
        bool act[3];
#pragma unroll
        for (int j = 0; j < 3; ++j) act[j] = (tb + j) < mynkt;  // wave-uniform

        // ---- S for active tiles ----
        f32x16 st[3][2];
#pragma unroll
        for (int j = 0; j < 3; ++j) {
          if (act[j]) {
            const bf16_t* Kb = &KV[bi][j][0][0];
            bf16x8 kf[2][4];
#pragma unroll
            for (int t = 0; t < 2; ++t)
#pragma unroll
              for (int d = 0; d < 4; ++d) {
                int row = 32 * t + l31;
                int col = ((d * 2 + hi) ^ (row & 7)) * 8;
                kf[t][d] = *(const bf16x8*)&Kb[row * 64 + col];
              }
#pragma unroll
            for (int t = 0; t < 2; ++t) {
#pragma unroll
              for (int r = 0; r < 16; ++r) st[j][t][r] = 0.f;
#pragma unroll
              for (int d = 0; d < 4; ++d) st[j][t] = mfma32(kf[t][d], qf[d], st[j][t]);
            }
            if (tb + j == mynkt - 1) {  // diagonal tile: causal mask
#pragma unroll
              for (int t = 0; t < 2; ++t)
#pragma unroll
                for (int r = 0; r < 16; ++r)
                  if ((tb + j) * 64 + 32 * t + CROW(r) > q0 + l31) st[j][t][r] = -1e30f;
            }
          }
        }

        // ---- merged online softmax over up to 192 keys (exp2 domain) ----
        float pm = -1e30f;
#pragma unroll
        for (int j = 0; j < 3; ++j)
          if (act[j])
#pragma unroll
            for (int t = 0; t < 2; ++t)
#pragma unroll
              for (int r = 0; r < 16; ++r) pm = fmaxf(pm, st[j][t][r]);
        pm = fmaxf(pm, __shfl_xor(pm, 32));
        if (!__all(pm - mrow <= 11.0f)) {  // defer-max
          float mn = fmaxf(mrow, pm);
          float scl = exp2f(mrow - mn);
          mrow = mn;
          lsum *= scl;
#pragma unroll
          for (int r = 0; r < 16; ++r) {
            float sr = __shfl(scl, CROW(r));
            o[0][r] *= sr;
            o[1][r] *= sr;
          }
        }

        // ---- per tile: exp -> pack -> PV (short st/pk lifetimes) ----
        float ps = 0.f;
#pragma unroll
        for (int j = 0; j < 3; ++j) {
          if (act[j]) {
#pragma unroll
            for (int t = 0; t < 2; ++t)
#pragma unroll
              for (int r = 0; r < 16; ++r) {
                float e = exp2f(st[j][t][r] - mrow);
                st[j][t][r] = e;
                ps += e;
              }
            unsigned pk[2][8];
#pragma unroll
            for (int t = 0; t < 2; ++t)
#pragma unroll
              for (int jj = 0; jj < 8; ++jj)
                pk[t][jj] = pk2(st[j][t][2 * jj], st[j][t][2 * jj + 1]);
            bf16x8 vf[2][4];
            unsigned vb = lds_addr(&KV[bi][j][1][0]);
#pragma unroll
            for (int n2 = 0; n2 < 2; ++n2)
#pragma unroll
              for (int ks = 0; ks < 4; ++ks) {
                int pn = 2 * n2 + (l31 >> 4);
                int k0 = ks * 16 + hi * 8;
                unsigned a = vb + pn * 2048 + k0 * 32 + l15 * 8;
                i32x2 lo = tr64(a);
                i32x2 hi4 = tr64o(a);
                union { unsigned u[4]; bf16x8 v; } uu;
                uu.u[0] = (unsigned)lo[0]; uu.u[1] = (unsigned)lo[1];
                uu.u[2] = (unsigned)hi4[0]; uu.u[3] = (unsigned)hi4[1];
                vf[n2][ks] = uu.v;
              }
            WAITL0;
#pragma unroll
            for (int ks = 0; ks < 4; ++ks) {
              const int t = ks >> 1, rb = (ks & 1) * 4;
              unsigned s0 = hi ? pk[t][rb] : pk[t][rb + 2];
              unsigned s1 = hi ? pk[t][rb + 1] : pk[t][rb + 3];
              unsigned r0 = (unsigned)__shfl_xor((int)s0, 32);
              unsigned r1 = (unsigned)__shfl_xor((int)s1, 32);
              union { unsigned u[4]; bf16x8 v; } w;
              if (hi == 0) {
                w.u[0] = pk[t][rb]; w.u[1] = pk[t][rb + 1]; w.u[2] = r0; w.u[3] = r1;
              } else {
                w.u[0] = r0; w.u[1] = r1; w.u[2] = pk[t][rb + 2]; w.u[3] = pk[t][rb + 3];
              }
              o[0] = mfma32(w.v, vf[0][ks], o[0]);
              o[1] = mfma32(w.v, vf[1][ks], o[1]);
            }
          }
        }
        ps += __shfl_xor(ps, 32);
        lsum += ps;
      }  // tb < mynkt
    }  // pi

    // ---- phase epilogue ----
#pragma unroll
    for (int r = 0; r < 16; ++r) {
      float li = __shfl(lsum, CROW(r));
      float inv = 1.0f / li;
      int qrow = q0 + CROW(r);
#pragma unroll
      for (int n2 = 0; n2 < 2; ++n2)
        Cg[(size_t)qrow * D_ + n2 * 32 + l31] = (bf16_t)(o[n2][r] * inv);
    }
  }  // phase
}

// ---------------- launch ----------------
extern "C" void kernel_launch(void* const* d_in, const int* in_sizes, int n_in,
                              void* d_out, int out_size, void* d_ws, size_t ws_size,
                              hipStream_t stream) {
  const float* x   = (const float*)d_in[0];
  const float* w_q = (const float*)d_in[1];
  const float* w_k = (const float*)d_in[2];
  const float* w_v = (const float*)d_in[3];
  const float* w_o = (const float*)d_in[4];

  const int M = B_ * T_;              // 4096
  const size_t XN = (size_t)M * D_;   // 4M
  const size_t WN = (size_t)D_ * D_;  // 1M

  bf16_t* ws = (bf16_t*)d_ws;
  bf16_t* xb   = ws;            // 4M
  bf16_t* wqb  = xb + XN;       // 3M (q,k,v) + 1M (o) contiguous
  bf16_t* wob  = wqb + 3 * WN;
  bf16_t* qkv  = wob + WN;      // [4096][3072] = 12M
  bf16_t* ctx  = qkv + (size_t)M * RS_;  // 4M

  cvt_all<<<dim3(1024, 8), 256, 0, stream>>>(x, w_q, w_k, w_v, w_o, ws);

  // fused QKV GEMM (XCD-swizzled 1-D grid): 768 blocks = 24 bx x 32 by
  gemm_nt<false, true><<<768, 256, 0, stream>>>(xb, wqb, qkv, M, RS_, D_, RS_ / 128);

  attn_fwd<<<dim3(B_ * H_, 8), 256, 0, stream>>>(qkv, ctx);

  // out-proj (XCD-swizzled 1-D grid): 512 blocks = 8 bx x 64 by
  gemm_nt64<<<512, 256, 0, stream>>>(ctx, wob, (float*)d_out, M, D_, D_, D_ / 128);
}

// Round 20
// 125.200 us; speedup vs baseline: 1.0352x; 1.0352x over previous
//
#include <hip/hip_runtime.h>
#include <hip/hip_bf16.h>

typedef __bf16 bf16_t;
typedef __attribute__((ext_vector_type(8))) __bf16 bf16x8;
typedef __attribute__((ext_vector_type(4))) __bf16 bf16x4;
typedef __attribute__((ext_vector_type(4))) float f32x4;
typedef __attribute__((ext_vector_type(16))) float f32x16;
typedef __attribute__((ext_vector_type(2))) int i32x2;

#define B_ 2
#define T_ 2048
#define D_ 1024
#define H_ 16
#define DH_ 64
#define RS_ 3072  // fused qkv row stride

static __device__ __forceinline__ f32x4 mfma16(bf16x8 a, bf16x8 b, f32x4 c) {
  return __builtin_amdgcn_mfma_f32_16x16x32_bf16(a, b, c, 0, 0, 0);
}
static __device__ __forceinline__ f32x16 mfma32(bf16x8 a, bf16x8 b, f32x16 c) {
  return __builtin_amdgcn_mfma_f32_32x32x16_bf16(a, b, c, 0, 0, 0);
}
static __device__ __forceinline__ void gld16(const bf16_t* g, bf16_t* l) {
  __builtin_amdgcn_global_load_lds(
      (const __attribute__((address_space(1))) unsigned int*)g,
      (__attribute__((address_space(3))) unsigned int*)l, 16, 0, 0);
}
static __device__ __forceinline__ unsigned lds_addr(const bf16_t* p) {
  return (unsigned)(uintptr_t)(const __attribute__((address_space(3))) bf16_t*)p;
}
static __device__ __forceinline__ i32x2 tr64(unsigned a) {
  i32x2 d;
  asm volatile("ds_read_b64_tr_b16 %0, %1" : "=v"(d) : "v"(a));
  return d;
}
static __device__ __forceinline__ i32x2 tr64o(unsigned a) {  // +128B (4 k-rows)
  i32x2 d;
  asm volatile("ds_read_b64_tr_b16 %0, %1 offset:128" : "=v"(d) : "v"(a));
  return d;
}
static __device__ __forceinline__ unsigned pk2(float lo, float hi2) {
  unsigned short a = __builtin_bit_cast(unsigned short, (bf16_t)lo);
  unsigned short b = __builtin_bit_cast(unsigned short, (bf16_t)hi2);
  return (unsigned)a | ((unsigned)b << 16);
}

#define WAITV3 { asm volatile("s_waitcnt vmcnt(3)" ::: "memory"); __builtin_amdgcn_sched_barrier(0); }
#define WAITV4 { asm volatile("s_waitcnt vmcnt(4)" ::: "memory"); __builtin_amdgcn_sched_barrier(0); }
#define WAITV8 { asm volatile("s_waitcnt vmcnt(8)" ::: "memory"); __builtin_amdgcn_sched_barrier(0); }
#define WAITV0 { asm volatile("s_waitcnt vmcnt(0)" ::: "memory"); __builtin_amdgcn_sched_barrier(0); }
#define BAR    { __builtin_amdgcn_s_barrier(); __builtin_amdgcn_sched_barrier(0); }
#define WAITL0 { asm volatile("s_waitcnt lgkmcnt(0)" ::: "memory"); __builtin_amdgcn_sched_barrier(0); }

// ---------------- fused fp32 -> bf16 conversion (x + 4 weights, one launch) ----------------
__global__ __launch_bounds__(256) void cvt_all(const float* __restrict__ x,
                                               const float* __restrict__ w0,
                                               const float* __restrict__ w1,
                                               const float* __restrict__ w2,
                                               const float* __restrict__ w3,
                                               bf16_t* __restrict__ out) {
  const int y = blockIdx.y;
  const float* in = (y < 4) ? (x + (size_t)y * 1048576)
                            : (y == 4 ? w0 : y == 5 ? w1 : y == 6 ? w2 : w3);
  bf16_t* o = out + (size_t)y * 1048576;
  int i = blockIdx.x * 256 + threadIdx.x;
  float4 f = reinterpret_cast<const float4*>(in)[i];
  bf16x4 v;
  v[0] = (bf16_t)f.x; v[1] = (bf16_t)f.y; v[2] = (bf16_t)f.z; v[3] = (bf16_t)f.w;
  reinterpret_cast<bf16x4*>(o)[i] = v;
}

// ---------------- NT GEMM 128x128 (R7 triple-buffer BK=32, vmcnt(4), XCD swizzle) ----------------
template <bool STORE_F32, bool QSCALE>
__global__ __launch_bounds__(256) void gemm_nt(const bf16_t* __restrict__ A,
                                               const bf16_t* __restrict__ Bm,
                                               void* __restrict__ Cv,
                                               int M, int N, int K, int nbx) {
  __shared__ __align__(16) bf16_t As[3][128 * 32];
  __shared__ __align__(16) bf16_t Bs[3][128 * 32];
  const int id = blockIdx.x;
  const int nwg = gridDim.x;
  const int cpx = nwg >> 3;                    // blocks per XCD (nwg % 8 == 0)
  const int swz = (id & 7) * cpx + (id >> 3);  // bijective XCD swizzle
  const int bx = swz % nbx, by = swz / nbx;
  const int tid = threadIdx.x, lane = tid & 63, wave = tid >> 6;
  const int l15 = lane & 15;
  const int brow = by * 128, bcol = bx * 128;
  const int row0 = (wave >> 1) * 64, col0 = (wave & 1) * 64;
  const float cscale = (QSCALE && bcol < 1024) ? 0.18033688011112042f : 1.0f;

  f32x4 acc[4][4];
#pragma unroll
  for (int m = 0; m < 4; ++m)
#pragma unroll
    for (int n = 0; n < 4; ++n) acc[m][n] = f32x4{0.f, 0.f, 0.f, 0.f};

  const int nst = K >> 5;
  const int srow = tid >> 2;
  const int sc8 = (tid & 3) * 8;
  auto stage = [&](int bi, int ks) {
    const int k0 = ks * 32;
#pragma unroll
    for (int i = 0; i < 2; ++i)
      gld16(A + (size_t)(brow + 64 * i + srow) * K + k0 + sc8,
            &As[bi][2048 * i + 512 * wave]);
#pragma unroll
    for (int i = 0; i < 2; ++i)
      gld16(Bm + (size_t)(bcol + 64 * i + srow) * K + k0 + sc8,
            &Bs[bi][2048 * i + 512 * wave]);
  };

  stage(0, 0);
  stage(1, 1);

#pragma unroll 1
  for (int ks = 0; ks < nst; ++ks) {
    if (ks + 1 < nst) { WAITV4 } else { WAITV0 }
    BAR;
    if (ks + 2 < nst) stage((ks + 2) % 3, ks + 2);

    const bf16_t* Ab = &As[ks % 3][0];
    const bf16_t* Bb = &Bs[ks % 3][0];
    const int ko = (lane >> 4) * 8;
    bf16x8 af[4], bfr[4];
#pragma unroll
    for (int m = 0; m < 4; ++m)
      af[m] = *(const bf16x8*)&Ab[(row0 + 16 * m + l15) * 32 + ko];
#pragma unroll
    for (int n = 0; n < 4; ++n)
      bfr[n] = *(const bf16x8*)&Bb[(col0 + 16 * n + l15) * 32 + ko];
    WAITL0;
#pragma unroll
    for (int m = 0; m < 4; ++m)
#pragma unroll
      for (int n = 0; n < 4; ++n) acc[m][n] = mfma16(af[m], bfr[n], acc[m][n]);
  }

  const int crow = brow + row0 + (lane >> 4) * 4;
  const int ccol = bcol + col0 + l15;
#pragma unroll
  for (int m = 0; m < 4; ++m)
#pragma unroll
    for (int n = 0; n < 4; ++n)
#pragma unroll
      for (int r = 0; r < 4; ++r) {
        size_t idx = (size_t)(crow + 16 * m + r) * N + (ccol + 16 * n);
        float v = acc[m][n][r] * cscale;
        if (STORE_F32) reinterpret_cast<float*>(Cv)[idx] = v;
        else reinterpret_cast<bf16_t*>(Cv)[idx] = (bf16_t)v;
      }
}

// ---------------- NT GEMM 64x128 (out-proj, XCD swizzle) ----------------
__global__ __launch_bounds__(256) void gemm_nt64(const bf16_t* __restrict__ A,
                                                 const bf16_t* __restrict__ Bm,
                                                 float* __restrict__ Cv,
                                                 int M, int N, int K, int nbx) {
  __shared__ __align__(16) bf16_t As[3][64 * 32];
  __shared__ __align__(16) bf16_t Bs[3][128 * 32];
  const int id = blockIdx.x;
  const int cpx = gridDim.x >> 3;
  const int swz = (id & 7) * cpx + (id >> 3);
  const int bx = swz % nbx, by = swz / nbx;
  const int tid = threadIdx.x, lane = tid & 63, wave = tid >> 6;
  const int l15 = lane & 15;
  const int brow = by * 64, bcol = bx * 128;
  const int row0 = (wave >> 1) * 32, col0 = (wave & 1) * 64;

  f32x4 acc[2][4];
#pragma unroll
  for (int m = 0; m < 2; ++m)
#pragma unroll
    for (int n = 0; n < 4; ++n) acc[m][n] = f32x4{0.f, 0.f, 0.f, 0.f};

  const int nst = K >> 5;
  const int sr = lane >> 2;
  const int sc8 = (lane & 3) * 8;
  auto stage = [&](int bi, int ks) {
    const int k0 = ks * 32;
    gld16(A + (size_t)(brow + 16 * wave + sr) * K + k0 + sc8, &As[bi][512 * wave]);
#pragma unroll
    for (int i = 0; i < 2; ++i)
      gld16(Bm + (size_t)(bcol + 64 * i + 16 * wave + sr) * K + k0 + sc8,
            &Bs[bi][2048 * i + 512 * wave]);
  };

  stage(0, 0);
  stage(1, 1);

#pragma unroll 1
  for (int ks = 0; ks < nst; ++ks) {
    if (ks + 1 < nst) { WAITV3 } else { WAITV0 }
    BAR;
    if (ks + 2 < nst) stage((ks + 2) % 3, ks + 2);

    const bf16_t* Ab = &As[ks % 3][0];
    const bf16_t* Bb = &Bs[ks % 3][0];
    const int ko = (lane >> 4) * 8;
    bf16x8 af[2], bfr[4];
#pragma unroll
    for (int m = 0; m < 2; ++m)
      af[m] = *(const bf16x8*)&Ab[(row0 + 16 * m + l15) * 32 + ko];
#pragma unroll
    for (int n = 0; n < 4; ++n)
      bfr[n] = *(const bf16x8*)&Bb[(col0 + 16 * n + l15) * 32 + ko];
    WAITL0;
#pragma unroll
    for (int m = 0; m < 2; ++m)
#pragma unroll
      for (int n = 0; n < 4; ++n) acc[m][n] = mfma16(af[m], bfr[n], acc[m][n]);
  }

  const int crow = brow + row0 + (lane >> 4) * 4;
  const int ccol = bcol + col0 + l15;
#pragma unroll
  for (int m = 0; m < 2; ++m)
#pragma unroll
    for (int n = 0; n < 4; ++n)
#pragma unroll
      for (int r = 0; r < 4; ++r)
        Cv[(size_t)(crow + 16 * m + r) * N + (ccol + 16 * n)] = acc[m][n][r];
}

// ---------------- causal flash attention: R15 pair-merge + store-drain fix ----------------
// Block = 256 thr (4 waves), grid (32 bh, 8 p). Pair-intervals: phase A = p+1,
// phase B = 16-p. Triple-buffered pairs (96KB LDS), counted vmcnt(8).
// RACE FIX (R19 post-timing failure): the phase epilogue's 32 global stores
// previously stayed outstanding into the next phase's counted WAITV8 window.
// The "drain oldest, keep newest N" vmcnt guarantee is HW-verified for LOADS
// only (m135); mixed store/load retirement order is not — occasionally the
// WAITV8 retired stores early and left staging loads unlanded -> corrupted K/V.
// Fix: WAITV0 after the epilogue stores, so counted waits only ever see loads.
#define CROW(r) ((((r) & 3) + 8 * ((r) >> 2)) + 4 * hi)

__global__ __launch_bounds__(256, 1) void attn_fwd(const bf16_t* __restrict__ qkv,
                                                   bf16_t* __restrict__ ctx) {
  __shared__ __align__(128) bf16_t KV[3][2][2][4096];  // [buf][tile][K|V][4096] = 96 KB
  const int tid = threadIdx.x;
  const int lane = tid & 63;
  const int wv = tid >> 6;
  const int bh = blockIdx.x, p = blockIdx.y;
  const int b = bh >> 4, h = bh & 15;
  const bf16_t* Qg = qkv + (size_t)b * T_ * RS_ + h * DH_;
  const bf16_t* Kg = Qg + 1024;
  const bf16_t* Vg = Qg + 2048;
  bf16_t* Cg = ctx + (size_t)b * T_ * D_ + h * DH_;

  const int hi = lane >> 5;
  const int l31 = lane & 31;
  const int l15 = lane & 15;

  // stage one 64-key tile into slot [bi][tp] (K swizzled rows, V 16-wide panels)
  auto stage_t = [&](int bi, int tp, int kt) {
    bf16_t* Kb = &KV[bi][tp][0][0];
    bf16_t* Vb = &KV[bi][tp][1][0];
#pragma unroll
    for (int i = 0; i < 2; ++i) {
      int c2 = i * 256 + tid;
      int r = c2 >> 3, g8 = (c2 & 7) ^ (r & 7);
      gld16(Kg + (size_t)(kt * 64 + r) * RS_ + g8 * 8, Kb + i * 2048 + wv * 512);
    }
#pragma unroll
    for (int i = 0; i < 2; ++i) {
      int c2 = i * 256 + tid;
      int pn = c2 >> 7, k = (c2 >> 1) & 63, half = c2 & 1;
      gld16(Vg + (size_t)(kt * 64 + k) * RS_ + pn * 16 + half * 8, Vb + i * 2048 + wv * 512);
    }
  };

#pragma unroll 1
  for (int phase = 0; phase < 2; ++phase) {
    const int c = phase ? (63 - 4 * p - wv) : (4 * p + wv);
    const int q0 = c * 32;
    const int mynkt = (c >> 1) + 1;                // 64-key tiles for my chunk
    const int maxp = phase ? (16 - p) : (p + 1);   // pair-intervals (block-uniform)

    BAR;  // previous phase's LDS reads fully retired before re-staging
    stage_t(0, 0, 0);
    stage_t(0, 1, 1);
    if (maxp > 1) { stage_t(1, 0, 2); stage_t(1, 1, 3); }

    bf16x8 qf[4];
#pragma unroll
    for (int d = 0; d < 4; ++d)
      qf[d] = *(const bf16x8*)&Qg[(size_t)(q0 + l31) * RS_ + d * 16 + hi * 8];

    f32x16 o[2];
#pragma unroll
    for (int n = 0; n < 2; ++n)
#pragma unroll
      for (int r = 0; r < 16; ++r) o[n][r] = 0.f;
    float mrow = -1e30f, lsum = 0.f;

#pragma unroll 1
    for (int pi = 0; pi < maxp; ++pi) {
      if (pi + 1 < maxp) { WAITV8 } else { WAITV0 }
      BAR;
      if (pi + 2 < maxp) {
        stage_t((pi + 2) % 3, 0, 2 * (pi + 2));
        stage_t((pi + 2) % 3, 1, 2 * (pi + 2) + 1);
      }

      const int t0 = 2 * pi, t1 = 2 * pi + 1;
      const bool act1 = t1 < mynkt;  // wave-uniform

      // ---- S for tile0 (always active: t0 < mynkt by construction) ----
      f32x16 st0[2], st1[2];
      {
        const bf16_t* Kb = &KV[pi % 3][0][0][0];
        bf16x8 kf[2][4];
#pragma unroll
        for (int t = 0; t < 2; ++t)
#pragma unroll
          for (int d = 0; d < 4; ++d) {
            int row = 32 * t + l31;
            int col = ((d * 2 + hi) ^ (row & 7)) * 8;
            kf[t][d] = *(const bf16x8*)&Kb[row * 64 + col];
          }
#pragma unroll
        for (int t = 0; t < 2; ++t) {
#pragma unroll
          for (int r = 0; r < 16; ++r) st0[t][r] = 0.f;
#pragma unroll
          for (int d = 0; d < 4; ++d) st0[t] = mfma32(kf[t][d], qf[d], st0[t]);
        }
      }
      if (t0 == mynkt - 1) {  // diagonal tile: causal mask
#pragma unroll
        for (int t = 0; t < 2; ++t)
#pragma unroll
          for (int r = 0; r < 16; ++r)
            if (t0 * 64 + 32 * t + CROW(r) > q0 + l31) st0[t][r] = -1e30f;
      }
      // ---- S for tile1 (if active) ----
      if (act1) {
        const bf16_t* Kb = &KV[pi % 3][1][0][0];
        bf16x8 kf[2][4];
#pragma unroll
        for (int t = 0; t < 2; ++t)
#pragma unroll
          for (int d = 0; d < 4; ++d) {
            int row = 32 * t + l31;
            int col = ((d * 2 + hi) ^ (row & 7)) * 8;
            kf[t][d] = *(const bf16x8*)&Kb[row * 64 + col];
          }
#pragma unroll
        for (int t = 0; t < 2; ++t) {
#pragma unroll
          for (int r = 0; r < 16; ++r) st1[t][r] = 0.f;
#pragma unroll
          for (int d = 0; d < 4; ++d) st1[t] = mfma32(kf[t][d], qf[d], st1[t]);
        }
        if (t1 == mynkt - 1) {
#pragma unroll
          for (int t = 0; t < 2; ++t)
#pragma unroll
            for (int r = 0; r < 16; ++r)
              if (t1 * 64 + 32 * t + CROW(r) > q0 + l31) st1[t][r] = -1e30f;
        }
      }

      // ---- merged online softmax over up to 128 keys (exp2 domain) ----
      float pm = -1e30f;
#pragma unroll
      for (int t = 0; t < 2; ++t)
#pragma unroll
        for (int r = 0; r < 16; ++r) pm = fmaxf(pm, st0[t][r]);
      if (act1) {
#pragma unroll
        for (int t = 0; t < 2; ++t)
#pragma unroll
          for (int r = 0; r < 16; ++r) pm = fmaxf(pm, st1[t][r]);
      }
      pm = fmaxf(pm, __shfl_xor(pm, 32));
      if (!__all(pm - mrow <= 11.0f)) {  // defer-max
        float mn = fmaxf(mrow, pm);
        float scl = exp2f(mrow - mn);
        mrow = mn;
        lsum *= scl;
#pragma unroll
        for (int r = 0; r < 16; ++r) {
          float sr = __shfl(scl, CROW(r));
          o[0][r] *= sr;
          o[1][r] *= sr;
        }
      }
      float ps = 0.f;
#pragma unroll
      for (int t = 0; t < 2; ++t)
#pragma unroll
        for (int r = 0; r < 16; ++r) {
          float e = exp2f(st0[t][r] - mrow);
          st0[t][r] = e;
          ps += e;
        }
      if (act1) {
#pragma unroll
        for (int t = 0; t < 2; ++t)
#pragma unroll
          for (int r = 0; r < 16; ++r) {
            float e = exp2f(st1[t][r] - mrow);
            st1[t][r] = e;
            ps += e;
          }
      }
      ps += __shfl_xor(ps, 32);
      lsum += ps;

      // ---- pack + PV tile0 ----
      {
        unsigned pk[2][8];
#pragma unroll
        for (int t = 0; t < 2; ++t)
#pragma unroll
          for (int j = 0; j < 8; ++j) pk[t][j] = pk2(st0[t][2 * j], st0[t][2 * j + 1]);
        bf16x8 vf[2][4];
        unsigned vb = lds_addr(&KV[pi % 3][0][1][0]);
#pragma unroll
        for (int n2 = 0; n2 < 2; ++n2)
#pragma unroll
          for (int ks = 0; ks < 4; ++ks) {
            int pn = 2 * n2 + (l31 >> 4);
            int k0 = ks * 16 + hi * 8;
            unsigned a = vb + pn * 2048 + k0 * 32 + l15 * 8;
            i32x2 lo = tr64(a);
            i32x2 hi4 = tr64o(a);
            union { unsigned u[4]; bf16x8 v; } uu;
            uu.u[0] = (unsigned)lo[0]; uu.u[1] = (unsigned)lo[1];
            uu.u[2] = (unsigned)hi4[0]; uu.u[3] = (unsigned)hi4[1];
            vf[n2][ks] = uu.v;
          }
        WAITL0;
#pragma unroll
        for (int ks = 0; ks < 4; ++ks) {
          const int t = ks >> 1, rb = (ks & 1) * 4;
          unsigned s0 = hi ? pk[t][rb] : pk[t][rb + 2];
          unsigned s1 = hi ? pk[t][rb + 1] : pk[t][rb + 3];
          unsigned r0 = (unsigned)__shfl_xor((int)s0, 32);
          unsigned r1 = (unsigned)__shfl_xor((int)s1, 32);
          union { unsigned u[4]; bf16x8 v; } w;
          if (hi == 0) {
            w.u[0] = pk[t][rb]; w.u[1] = pk[t][rb + 1]; w.u[2] = r0; w.u[3] = r1;
          } else {
            w.u[0] = r0; w.u[1] = r1; w.u[2] = pk[t][rb + 2]; w.u[3] = pk[t][rb + 3];
          }
          o[0] = mfma32(w.v, vf[0][ks], o[0]);
          o[1] = mfma32(w.v, vf[1][ks], o[1]);
        }
      }
      // ---- pack + PV tile1 ----
      if (act1) {
        unsigned pk[2][8];
#pragma unroll
        for (int t = 0; t < 2; ++t)
#pragma unroll
          for (int j = 0; j < 8; ++j) pk[t][j] = pk2(st1[t][2 * j], st1[t][2 * j + 1]);
        bf16x8 vf[2][4];
        unsigned vb = lds_addr(&KV[pi % 3][1][1][0]);
#pragma unroll
        for (int n2 = 0; n2 < 2; ++n2)
#pragma unroll
          for (int ks = 0; ks < 4; ++ks) {
            int pn = 2 * n2 + (l31 >> 4);
            int k0 = ks * 16 + hi * 8;
            unsigned a = vb + pn * 2048 + k0 * 32 + l15 * 8;
            i32x2 lo = tr64(a);
            i32x2 hi4 = tr64o(a);
            union { unsigned u[4]; bf16x8 v; } uu;
            uu.u[0] = (unsigned)lo[0]; uu.u[1] = (unsigned)lo[1];
            uu.u[2] = (unsigned)hi4[0]; uu.u[3] = (unsigned)hi4[1];
            vf[n2][ks] = uu.v;
          }
        WAITL0;
#pragma unroll
        for (int ks = 0; ks < 4; ++ks) {
          const int t = ks >> 1, rb = (ks & 1) * 4;
          unsigned s0 = hi ? pk[t][rb] : pk[t][rb + 2];
          unsigned s1 = hi ? pk[t][rb + 1] : pk[t][rb + 3];
          unsigned r0 = (unsigned)__shfl_xor((int)s0, 32);
          unsigned r1 = (unsigned)__shfl_xor((int)s1, 32);
          union { unsigned u[4]; bf16x8 v; } w;
          if (hi == 0) {
            w.u[0] = pk[t][rb]; w.u[1] = pk[t][rb + 1]; w.u[2] = r0; w.u[3] = r1;
          } else {
            w.u[0] = r0; w.u[1] = r1; w.u[2] = pk[t][rb + 2]; w.u[3] = pk[t][rb + 3];
          }
          o[0] = mfma32(w.v, vf[0][ks], o[0]);
          o[1] = mfma32(w.v, vf[1][ks], o[1]);
        }
      }
    }  // pi

    // ---- phase epilogue ----
#pragma unroll
    for (int r = 0; r < 16; ++r) {
      float li = __shfl(lsum, CROW(r));
      float inv = 1.0f / li;
      int qrow = q0 + CROW(r);
#pragma unroll
      for (int n2 = 0; n2 < 2; ++n2)
        Cg[(size_t)qrow * D_ + n2 * 32 + l31] = (bf16_t)(o[n2][r] * inv);
    }
    // RACE FIX: drain epilogue stores so the next phase's counted vmcnt waits
    // only ever cover loads (mixed store/load retirement order is unverified).
    WAITV0;
  }  // phase
}

// ---------------- launch ----------------
extern "C" void kernel_launch(void* const* d_in, const int* in_sizes, int n_in,
                              void* d_out, int out_size, void* d_ws, size_t ws_size,
                              hipStream_t stream) {
  const float* x   = (const float*)d_in[0];
  const float* w_q = (const float*)d_in[1];
  const float* w_k = (const float*)d_in[2];
  const float* w_v = (const float*)d_in[3];
  const float* w_o = (const float*)d_in[4];

  const int M = B_ * T_;              // 4096
  const size_t XN = (size_t)M * D_;   // 4M
  const size_t WN = (size_t)D_ * D_;  // 1M

  bf16_t* ws = (bf16_t*)d_ws;
  bf16_t* xb   = ws;            // 4M
  bf16_t* wqb  = xb + XN;       // 3M (q,k,v) + 1M (o) contiguous
  bf16_t* wob  = wqb + 3 * WN;
  bf16_t* qkv  = wob + WN;      // [4096][3072] = 12M
  bf16_t* ctx  = qkv + (size_t)M * RS_;  // 4M

  cvt_all<<<dim3(1024, 8), 256, 0, stream>>>(x, w_q, w_k, w_v, w_o, ws);

  // fused QKV GEMM (XCD-swizzled 1-D grid): 768 blocks = 24 bx x 32 by
  gemm_nt<false, true><<<768, 256, 0, stream>>>(xb, wqb, qkv, M, RS_, D_, RS_ / 128);

  attn_fwd<<<dim3(B_ * H_, 8), 256, 0, stream>>>(qkv, ctx);

  // out-proj (XCD-swizzled 1-D grid): 512 blocks = 8 bx x 64 by
  gemm_nt64<<<512, 256, 0, stream>>>(ctx, wob, (float*)d_out, M, D_, D_, D_ / 128);
}